// Round 3
// baseline (651.009 us; speedup 1.0000x reference)
//
#include <hip/hip_runtime.h>
#include <math.h>

#define B_ 2
#define N_ 6
#define D_ 59
#define FH 32
#define FW 88
#define C_ 80
#define NX 360
#define NY 360
#define P_PER_B (N_*D_*FH*FW)     // 996,864
#define NPTS (B_*P_PER_B)         // 1,993,728 = 7788*256
#define NCELL (NX*NY)             // 129,600
#define NC (B_*NCELL)             // 259,200 cells
#define NCP (254*1024)            // 260,096 padded
#define GCELLS 45                 // cells per gather group (360 = 8*45)
#define NGRP (NC/GCELLS)          // 5,760
#define GATHER_BLOCKS (NGRP*2)    // 11,520 (x2 channel halves)

// Static device scratch; every read location rewritten each launch (graph/replay safe).
__device__ float g_inv[B_*N_*16];
__device__ int   g_code[NPTS];     // cell id or -1
__device__ int   g_cnt[NCP];       // per-cell counts (padded, zeroed each launch)
__device__ int   g_escan[NCP];     // block-local exclusive scan
__device__ int   g_bsum[254];
__device__ int   g_bpre[254];
__device__ int   g_offs[NC+1];     // global exclusive offsets
__device__ int   g_cur[NC];        // fill cursors (= offs, bumped)
__device__ int   g_plist[NPTS];    // cell-sorted point ids

// ---- 1) zero counts + invert the 12 lidar2img matrices (block 0)
__global__ void k_prep(const float* __restrict__ l2i) {
  int i = blockIdx.x*1024 + threadIdx.x;
  if (i < NCP) g_cnt[i] = 0;
  if (blockIdx.x == 0 && threadIdx.x < B_*N_) {
    int m = threadIdx.x;
    double a[4][4], inv[4][4];
    for (int r=0;r<4;r++) for (int j=0;j<4;j++){
      a[r][j] = (double)l2i[m*16+r*4+j];
      inv[r][j] = (r==j)?1.0:0.0;
    }
    for (int k=0;k<4;k++){
      int p=k; double mx=fabs(a[k][k]);
      for (int r=k+1;r<4;r++){ double v=fabs(a[r][k]); if (v>mx){mx=v;p=r;} }
      if (p!=k){
        for (int j=0;j<4;j++){
          double t=a[k][j]; a[k][j]=a[p][j]; a[p][j]=t;
          t=inv[k][j]; inv[k][j]=inv[p][j]; inv[p][j]=t;
        }
      }
      double pi = 1.0/a[k][k];
      for (int j=0;j<4;j++){ a[k][j]*=pi; inv[k][j]*=pi; }
      for (int r=0;r<4;r++) if (r!=k){
        double f=a[r][k];
        for (int j=0;j<4;j++){ a[r][j]-=f*a[k][j]; inv[r][j]-=f*inv[k][j]; }
      }
    }
    for (int r=0;r<4;r++) for (int j=0;j<4;j++)
      g_inv[m*16+r*4+j] = (float)inv[r][j];
  }
}

// ---- 2) geometry -> cell code + per-cell count. f32, no fp contraction (match numpy).
__global__ void k_geom(const float* __restrict__ itrans, const float* __restrict__ iscale) {
#pragma clang fp contract(off)
  int p = blockIdx.x*256 + threadIdx.x;          // grid exact: 7788*256 = NPTS
  int b  = p / P_PER_B;
  int r  = p - b*P_PER_B;
  int n  = r / (D_*FH*FW);
  int r2 = r - n*(D_*FH*FW);
  int d  = r2 / (FH*FW);
  int r3 = r2 - d*(FH*FW);
  int h  = r3 / FW;
  int w  = r3 - h*FW;
  int bn = b*N_ + n;

  float xw = (float)((double)w * (703.0/87.0));   // np.linspace in f64, rounded
  float yh = (float)((double)h * (255.0/31.0));
  float dd = (float)(d + 1);                      // ds = 1..59

  float t0 = itrans[bn*3+0], t1 = itrans[bn*3+1], t2 = itrans[bn*3+2];
  float s  = iscale[bn];

  float px = xw + t0, py = yh + t1, pd = dd + t2;
  float x0 = px / s, x1 = py / s;
  float p0 = x0*pd, p1 = x1*pd, p2 = pd;

  const float* iv = &g_inv[bn*16];
  float gx = ((iv[0]*p0 + iv[1]*p1) + iv[2]*p2)  + iv[3]*1.0f;
  float gy = ((iv[4]*p0 + iv[5]*p1) + iv[6]*p2)  + iv[7]*1.0f;
  float gz = ((iv[8]*p0 + iv[9]*p1) + iv[10]*p2) + iv[11]*1.0f;

  int vx = (int)((gx + 54.0f) / 0.3f);   // trunc toward zero == astype(int32)
  int vy = (int)((gy + 54.0f) / 0.3f);
  int vz = (int)((gz + 10.0f) / 20.0f);

  bool ok = (vx>=0) & (vx<NX) & (vy>=0) & (vy<NY) & (vz>=0) & (vz<1);
  int cell = b*NCELL + vx*NY + vy;
  g_code[p] = ok ? cell : -1;
  if (ok) atomicAdd(&g_cnt[cell], 1);
}

// ---- 3a) per-block exclusive scan (1024) over counts
__global__ void k_scanA() {
  __shared__ int sd[1024];
  int t = threadIdx.x;
  int i = blockIdx.x*1024 + t;
  int v = g_cnt[i];
  sd[t] = v;
  for (int off=1; off<1024; off<<=1) {
    __syncthreads();
    int x = (t >= off) ? sd[t-off] : 0;
    __syncthreads();
    sd[t] += x;
  }
  g_escan[i] = sd[t] - v;
  if (t == 1023) g_bsum[blockIdx.x] = sd[1023];
}

// ---- 3b) scan the 254 block sums
__global__ void k_scanB() {
  __shared__ int sd[256];
  int t = threadIdx.x;
  int v = (t < 254) ? g_bsum[t] : 0;
  sd[t] = v;
  for (int off=1; off<256; off<<=1) {
    __syncthreads();
    int x = (t >= off) ? sd[t-off] : 0;
    __syncthreads();
    sd[t] += x;
  }
  if (t < 254) g_bpre[t] = sd[t] - v;
  if (t == 255) g_offs[NC] = sd[255];   // total valid count
}

// ---- 3c) add back -> global offsets + cursors
__global__ void k_scanC() {
  int i = blockIdx.x*1024 + threadIdx.x;
  if (i < NC) {
    int o = g_escan[i] + g_bpre[blockIdx.x];
    g_offs[i] = o;
    g_cur[i]  = o;
  }
}

// ---- 4) fill cell-sorted point list
__global__ void k_fill() {
  int p = blockIdx.x*256 + threadIdx.x;
  int c = g_code[p];
  if (c >= 0) {
    int pos = atomicAdd(&g_cur[c], 1);
    g_plist[pos] = p;
  }
}

// ---- 5) gather: block = (45-cell column segment, channel half). Exclusive
// ownership -> plain stores to d_out in final layout. Hot columns (x~182)
// dispatched first via |x-182| ordering so their tails hide under the rest.
__global__ void __launch_bounds__(320) k_gather(const float* __restrict__ feats,
                                                float* __restrict__ out) {
  __shared__ float acc[GCELLS*41];   // [cell][ch] pad 41: conflict-free
  __shared__ int soffs[GCELLS+1];

  int gid = blockIdx.x;
  int r = gid >> 5;                  // x-rank 0..359
  int rest = gid & 31;               // b(2) x yg(8) x h(2)
  int off = (r+1) >> 1;
  int x = (r & 1) ? 182 - off : 182 + off;
  x = ((x % 360) + 360) % 360;       // bijective |x-182| ordering
  int b  = rest >> 4;
  int yg = (rest >> 1) & 7;
  int h  = rest & 1;
  int c0 = b*NCELL + x*NY + yg*GCELLS;

  int tid = threadIdx.x;
  int c4r  = tid % 10;               // float4-group within half
  int slot = tid / 10;               // 0..31
  int c4 = h*10 + c4r;               // global float4-group 0..19

  for (int e = tid; e < GCELLS*41; e += 320) acc[e] = 0.f;
  if (tid < GCELLS+1) soffs[tid] = g_offs[c0 + tid];
  __syncthreads();

  const float4* f4 = (const float4*)feats;
  for (int ci = 0; ci < GCELLS; ++ci) {
    int s = soffs[ci], e = soffs[ci+1];
    int n = e - s;
    if (n == 0) continue;
    float ax=0.f, ay=0.f, az=0.f, aw=0.f;
    bool any = false;
    for (int j = slot; j < n; j += 32) {
      int p = g_plist[s + j];
      float4 v = f4[p*20 + c4];
      ax += v.x; ay += v.y; az += v.z; aw += v.w;
      any = true;
    }
    if (any) {
      float* a = &acc[ci*41 + c4r*4];
      atomicAdd(a+0, ax); atomicAdd(a+1, ay);
      atomicAdd(a+2, az); atomicAdd(a+3, aw);
    }
  }
  __syncthreads();

  // store 40 channels x 45 cells to out[(b*80 + h*40 + cc)][x][y0..y0+45)
  size_t base = ((size_t)(b*C_ + h*40))*NCELL + (size_t)x*NY + yg*GCELLS;
  for (int e = tid; e < 40*GCELLS; e += 320) {
    int cc = e / GCELLS, y = e - cc*GCELLS;
    out[base + (size_t)cc*NCELL + y] = acc[y*41 + cc];
  }
}

extern "C" void kernel_launch(void* const* d_in, const int* in_sizes, int n_in,
                              void* d_out, int out_size, void* d_ws, size_t ws_size,
                              hipStream_t stream) {
  const float* feats  = (const float*)d_in[0];
  const float* itrans = (const float*)d_in[1];
  const float* iscale = (const float*)d_in[2];
  const float* l2i    = (const float*)d_in[3];
  float* out = (float*)d_out;

  k_prep<<<254, 1024, 0, stream>>>(l2i);
  k_geom<<<NPTS/256, 256, 0, stream>>>(itrans, iscale);   // 7,788 blocks
  k_scanA<<<254, 1024, 0, stream>>>();
  k_scanB<<<1, 256, 0, stream>>>();
  k_scanC<<<254, 1024, 0, stream>>>();
  k_fill<<<NPTS/256, 256, 0, stream>>>();                 // 7,788 blocks
  k_gather<<<GATHER_BLOCKS, 320, 0, stream>>>(feats, out);// 11,520 blocks
}

// Round 4
// 185.784 us; speedup vs baseline: 3.5041x; 3.5041x over previous
//
#include <hip/hip_runtime.h>
#include <math.h>

#define B_ 2
#define N_ 6
#define D_ 59
#define FH 32
#define FW 88
#define C_ 80
#define NX 360
#define NY 360
#define P_PER_B (N_*D_*FH*FW)     // 996,864
#define NPTS (B_*P_PER_B)         // 1,993,728 = 7788*256
#define NCELL (NX*NY)             // 129,600
#define NC (B_*NCELL)             // 259,200 cells
#define NCP (254*1024)            // 260,096 padded (= 254*256 int4)
#define OUT4 (B_*C_*NCELL/4)      // 5,184,000 float4 in out
#define SUB 32                    // points per gather slot

// Static device scratch; every read location rewritten each launch (replay safe).
__device__ float g_inv[B_*N_*16];
__device__ int   g_code[NPTS];     // cell id or -1
__device__ int   g_cnt[NCP];       // per-cell counts (padded, zeroed each launch)
__device__ int   g_escan[NCP];
__device__ int   g_bsum[254];
__device__ int   g_bpre[254];
__device__ int   g_offs[NC+1];     // global exclusive offsets (+ total at [NC])
__device__ int   g_cur[NC];        // fill cursors
__device__ int   g_plist[NPTS];    // cell-sorted point ids
__device__ int   g_clist[NPTS];    // cell id per sorted position

// ---- 1) init: zero d_out (83MB) + zero counts + invert the 12 matrices
__global__ void k_init(const float* __restrict__ l2i, float* __restrict__ out) {
  int i = blockIdx.x*256 + threadIdx.x;            // grid exact: OUT4/256 blocks
  ((float4*)out)[i] = make_float4(0.f,0.f,0.f,0.f);
  if (blockIdx.x < 254) {
    ((int4*)g_cnt)[i] = make_int4(0,0,0,0);
  }
  if (blockIdx.x == 20249 && threadIdx.x < B_*N_) {
    int m = threadIdx.x;
    double a[4][4], inv[4][4];
    for (int r=0;r<4;r++) for (int j=0;j<4;j++){
      a[r][j] = (double)l2i[m*16+r*4+j];
      inv[r][j] = (r==j)?1.0:0.0;
    }
    for (int k=0;k<4;k++){
      int p=k; double mx=fabs(a[k][k]);
      for (int r=k+1;r<4;r++){ double v=fabs(a[r][k]); if (v>mx){mx=v;p=r;} }
      if (p!=k){
        for (int j=0;j<4;j++){
          double t=a[k][j]; a[k][j]=a[p][j]; a[p][j]=t;
          t=inv[k][j]; inv[k][j]=inv[p][j]; inv[p][j]=t;
        }
      }
      double pi = 1.0/a[k][k];
      for (int j=0;j<4;j++){ a[k][j]*=pi; inv[k][j]*=pi; }
      for (int r=0;r<4;r++) if (r!=k){
        double f=a[r][k];
        for (int j=0;j<4;j++){ a[r][j]-=f*a[k][j]; inv[r][j]-=f*inv[k][j]; }
      }
    }
    for (int r=0;r<4;r++) for (int j=0;j<4;j++)
      g_inv[m*16+r*4+j] = (float)inv[r][j];
  }
}

// ---- 2) geometry -> cell code + wave-collapsed per-cell counts
__global__ void k_geom(const float* __restrict__ itrans, const float* __restrict__ iscale) {
#pragma clang fp contract(off)
  int p = blockIdx.x*256 + threadIdx.x;            // grid exact: NPTS/256
  int b  = p / P_PER_B;
  int r  = p - b*P_PER_B;
  int n  = r / (D_*FH*FW);
  int r2 = r - n*(D_*FH*FW);
  int d  = r2 / (FH*FW);
  int r3 = r2 - d*(FH*FW);
  int h  = r3 / FW;
  int w  = r3 - h*FW;
  int bn = b*N_ + n;

  float xw = (float)((double)w * (703.0/87.0));    // np.linspace in f64, rounded
  float yh = (float)((double)h * (255.0/31.0));
  float dd = (float)(d + 1);                       // ds = 1..59

  float t0 = itrans[bn*3+0], t1 = itrans[bn*3+1], t2 = itrans[bn*3+2];
  float s  = iscale[bn];

  float px = xw + t0, py = yh + t1, pd = dd + t2;
  float x0 = px / s, x1 = py / s;
  float p0 = x0*pd, p1 = x1*pd, p2 = pd;

  const float* iv = &g_inv[bn*16];
  float gx = ((iv[0]*p0 + iv[1]*p1) + iv[2]*p2)  + iv[3]*1.0f;
  float gy = ((iv[4]*p0 + iv[5]*p1) + iv[6]*p2)  + iv[7]*1.0f;
  float gz = ((iv[8]*p0 + iv[9]*p1) + iv[10]*p2) + iv[11]*1.0f;

  int vx = (int)((gx + 54.0f) / 0.3f);             // trunc == astype(int32)
  int vy = (int)((gy + 54.0f) / 0.3f);
  int vz = (int)((gz + 10.0f) / 20.0f);

  bool ok = (vx>=0) & (vx<NX) & (vy>=0) & (vy<NY) & (vz>=0) & (vz<1);
  int code = ok ? (b*NCELL + vx*NY + vy) : -1;
  g_code[p] = code;

  int lane = threadIdx.x & 63;
  int prev = __shfl_up(code, 1);
  bool leader = (lane == 0) || (code != prev);
  unsigned long long m = __ballot(leader);
  if (leader && code >= 0) {
    unsigned long long above = (lane < 63) ? (m >> (lane+1)) : 0ULL;
    int len = above ? __ffsll(above) : (64 - lane);
    atomicAdd(&g_cnt[code], len);
  }
}

// ---- 3a) per-block exclusive scan (1024) over counts
__global__ void k_scanA() {
  __shared__ int sd[1024];
  int t = threadIdx.x;
  int i = blockIdx.x*1024 + t;
  int v = g_cnt[i];
  sd[t] = v;
  for (int off=1; off<1024; off<<=1) {
    __syncthreads();
    int x = (t >= off) ? sd[t-off] : 0;
    __syncthreads();
    sd[t] += x;
  }
  g_escan[i] = sd[t] - v;
  if (t == 1023) g_bsum[blockIdx.x] = sd[1023];
}

// ---- 3b) scan the 254 block sums
__global__ void k_scanB() {
  __shared__ int sd[256];
  int t = threadIdx.x;
  int v = (t < 254) ? g_bsum[t] : 0;
  sd[t] = v;
  for (int off=1; off<256; off<<=1) {
    __syncthreads();
    int x = (t >= off) ? sd[t-off] : 0;
    __syncthreads();
    sd[t] += x;
  }
  if (t < 254) g_bpre[t] = sd[t] - v;
  if (t == 255) g_offs[NC] = sd[255];              // total valid count
}

// ---- 3c) add back -> global offsets + cursors
__global__ void k_scanC() {
  int i = blockIdx.x*1024 + threadIdx.x;
  if (i < NC) {
    int o = g_escan[i] + g_bpre[blockIdx.x];
    g_offs[i] = o;
    g_cur[i]  = o;
  }
}

// ---- 4) fill cell-sorted lists, wave-collapsed cursor bumps
__global__ void k_fill() {
  int p = blockIdx.x*256 + threadIdx.x;            // grid exact
  int code = g_code[p];
  int lane = threadIdx.x & 63;
  int prev = __shfl_up(code, 1);
  bool leader = (lane == 0) || (code != prev);
  unsigned long long m = __ballot(leader);
  unsigned long long mask_le = (lane==63) ? ~0ULL : ((1ULL << (lane+1)) - 1ULL);
  int leaderLane = 63 - __clzll(m & mask_le);
  int pos0 = 0;
  if (leader && code >= 0) {
    unsigned long long above = (lane < 63) ? (m >> (lane+1)) : 0ULL;
    int len = above ? __ffsll(above) : (64 - lane);
    pos0 = atomicAdd(&g_cur[code], len);
  }
  pos0 = __shfl(pos0, leaderLane);
  if (code >= 0) {
    int pos = pos0 + (lane - leaderLane);
    g_plist[pos] = p;
    g_clist[pos] = code;
  }
}

// ---- 5) load-balanced gather: slot = SUB consecutive sorted points, thread =
// (slot, c4). Run-collapse; exclusive cells -> plain stores, boundary -> atomics.
__device__ __forceinline__ void flush_run(float* __restrict__ out, int c, int c4,
                                          int s0, int s1,
                                          float ax, float ay, float az, float aw) {
  int o0 = g_offs[c], o1 = g_offs[c+1];
  int b = c / NCELL;
  int xy = c - b*NCELL;
  float* dst = out + (size_t)(b*C_ + c4*4)*NCELL + xy;
  if (o0 >= s0 && o1 <= s1) {                      // exclusive owner
    dst[0]       = ax;
    dst[NCELL]   = ay;
    dst[2*NCELL] = az;
    dst[3*NCELL] = aw;
  } else {
    atomicAdd(dst,         ax);
    atomicAdd(dst+NCELL,   ay);
    atomicAdd(dst+2*NCELL, az);
    atomicAdd(dst+3*NCELL, aw);
  }
}

__global__ void __launch_bounds__(320) k_gather(const float* __restrict__ feats,
                                                float* __restrict__ out) {
  int T = g_offs[NC];
  int nslots = (T + SUB - 1) / SUB;
  int c4 = threadIdx.x % 20;
  int slotInBlk = threadIdx.x / 20;                // 0..15
  const float4* f4 = (const float4*)feats;

  for (int ss = blockIdx.x*16 + slotInBlk; ss < nslots; ss += gridDim.x*16) {
    int s0 = ss*SUB;
    int s1 = min(s0 + SUB, T);
    int cur = g_clist[s0];
    float ax=0.f, ay=0.f, az=0.f, aw=0.f;
    for (int j = s0; j < s1; ++j) {
      int c = g_clist[j];
      if (c != cur) {
        flush_run(out, cur, c4, s0, s1, ax, ay, az, aw);
        cur = c; ax=ay=az=aw=0.f;
      }
      int p = g_plist[j];
      float4 v = f4[(size_t)p*20 + c4];
      ax += v.x; ay += v.y; az += v.z; aw += v.w;
    }
    flush_run(out, cur, c4, s0, s1, ax, ay, az, aw);
  }
}

extern "C" void kernel_launch(void* const* d_in, const int* in_sizes, int n_in,
                              void* d_out, int out_size, void* d_ws, size_t ws_size,
                              hipStream_t stream) {
  const float* feats  = (const float*)d_in[0];
  const float* itrans = (const float*)d_in[1];
  const float* iscale = (const float*)d_in[2];
  const float* l2i    = (const float*)d_in[3];
  float* out = (float*)d_out;

  k_init<<<OUT4/256, 256, 0, stream>>>(l2i, out);         // 20,250 blocks
  k_geom<<<NPTS/256, 256, 0, stream>>>(itrans, iscale);   // 7,788 blocks
  k_scanA<<<254, 1024, 0, stream>>>();
  k_scanB<<<1, 256, 0, stream>>>();
  k_scanC<<<254, 1024, 0, stream>>>();
  k_fill<<<NPTS/256, 256, 0, stream>>>();                 // 7,788 blocks
  k_gather<<<1024, 320, 0, stream>>>(feats, out);         // 1,024 blocks
}